// Round 11
// baseline (149.214 us; speedup 1.0000x reference)
//
#include <hip/hip_runtime.h>
#include <math.h>

#define TOPK 4
#define NQ 13   // 13 independent float4 loads = 52-float window (mean seg 32 + 3.5 sigma)

// One thread per node; whole segment loaded as NQ INDEPENDENT float4s issued
// back-to-back (chain depth 1, per-lane MLP ~13), then one masked consume
// pass. __launch_bounds__(256,4) caps VGPR at 128 so the 52-float window
// stays in registers (R6 failed because the default bound chose VGPR=32 and
// serialized the loads). No LDS -> no 8-wave/CU cap: 16 waves/CU.
__global__ __launch_bounds__(256, 4) void segment_top4_kernel(
    const int* __restrict__ row_ptr,
    const float* __restrict__ scores,
    float* __restrict__ vals_out,   // [N,4] float32
    float* __restrict__ idx_out,    // [N,4] indices as float32
    int n_nodes, int n_edges)
{
    int node = blockIdx.x * 256 + threadIdx.x;
    if (node >= n_nodes) return;

    int sb = row_ptr[node];
    int se = row_ptr[node + 1];
    int lo = sb & ~3;                 // 16B-aligned window start
    int clamp_hi = n_edges - 4;

    // ---- issue all window loads, fully independent ----
    float4 r[NQ];
#pragma unroll
    for (int j = 0; j < NQ; ++j) {
        int src = lo + 4 * j;
        src = src < clamp_hi ? src : clamp_hi;   // in-bounds; garbage masked below
        r[j] = *(const float4*)(scores + src);
    }

    float v0 = -INFINITY, v1 = -INFINITY, v2 = -INFINITY, v3 = -INFINITY;
    int   i0 = -1, i1 = -1, i2 = -1, i3 = -1;

    // Branchless insertion, strict '>' keeps the smaller edge index on ties
    // (elements processed in increasing e) — matches reference. -inf never inserts.
    auto ins = [&](float sc, int id) {
        bool g0 = sc > v0, g1 = sc > v1, g2 = sc > v2, g3 = sc > v3;
        v3 = g3 ? (g2 ? v2 : sc) : v3;  i3 = g3 ? (g2 ? i2 : id) : i3;
        v2 = g2 ? (g1 ? v1 : sc) : v2;  i2 = g2 ? (g1 ? i1 : id) : i2;
        v1 = g1 ? (g0 ? v0 : sc) : v1;  i1 = g1 ? (g0 ? i0 : id) : i1;
        v0 = g0 ? sc : v0;              i0 = g0 ? id : i0;
    };

    // Single-compare in-segment mask: position p (0..51) is valid iff
    // (unsigned)(p - off) < len, where off = sb-lo in [0,3], len = se-sb.
    unsigned off = (unsigned)(sb - lo);
    unsigned len = (unsigned)(se - sb);
#pragma unroll
    for (int j = 0; j < NQ; ++j) {
        int p = 4 * j;
        ins((unsigned)(p     - off) < len ? r[j].x : -INFINITY, lo + p);
        ins((unsigned)(p + 1 - off) < len ? r[j].y : -INFINITY, lo + p + 1);
        ins((unsigned)(p + 2 - off) < len ? r[j].z : -INFINITY, lo + p + 2);
        ins((unsigned)(p + 3 - off) < len ? r[j].w : -INFINITY, lo + p + 3);
    }
    // Tail for segments longer than the window (P ~ 2e-4 per lane).
    for (int e = lo + 4 * NQ; e < se; ++e) ins(scores[e], e);

    float4 vo = make_float4(v0, v1, v2, v3);
    *(float4*)(vals_out + (size_t)node * 4) = vo;
    float4 io = make_float4((float)i0, (float)i1, (float)i2, (float)i3);
    *(float4*)(idx_out + (size_t)node * 4) = io;
}

extern "C" void kernel_launch(void* const* d_in, const int* in_sizes, int n_in,
                              void* d_out, int out_size, void* d_ws, size_t ws_size,
                              hipStream_t stream)
{
    const int*   row_ptr = (const int*)d_in[0];
    const float* scores  = (const float*)d_in[1];
    int n_nodes = in_sizes[0] - 1;
    int n_edges = in_sizes[1];

    float* out      = (float*)d_out;
    float* vals_out = out;                           // first N*4 floats
    float* idx_out  = out + (size_t)n_nodes * TOPK;  // next N*4 floats (idx as f32)

    int blocks = (n_nodes + 255) / 256;
    segment_top4_kernel<<<blocks, 256, 0, stream>>>(
        row_ptr, scores, vals_out, idx_out, n_nodes, n_edges);
}